// Round 11
// baseline (241.786 us; speedup 1.0000x reference)
//
#include <hip/hip_runtime.h>
#include <math.h>

// ---------------------------------------------------------------------------
// Pipeline v7 — two-level dst sort + wave-cooperative SEGMENTED-REDUCTION agg.
// r10 analysis: scalar-CSR agg residuals = lane imbalance (wave waits on
// max-degree lane ~2x mean) + 64-distinct-lines per file-load instruction +
// file stream thrashing q/u out of L2 (agg2 FETCH 80MB). v7 agg kernels:
// consecutive entries -> consecutive lanes (1 instr = 4 lines, nt-safe since
// each line is consumed by exactly one instruction), per-edge gather,
// 6-step shfl segmented scan by dstlo, ONE LDS atomic per run tail (~E/16).
//   k_bucket : radix pass 1 (dst>>10), one LDS atomic/edge (rank-first),
//              shuffle scan, coalesced run write-out.
//   k_sort   : radix pass 2 (dst&1023); writes back FULL sorted entries
//              (src<<10|dstlo); rank atomic == degree histogram; fused
//              dinv / u = bf16(x*dinv) epilogue. No CSR start[] needed.
//   k_agg1   : segmented-reduce u[src] -> MLP 1->16->2 -> q packed 2xbf16.
//   k_agg2   : segmented-reduce q[src] (2 planes) -> log_softmax.
// ---------------------------------------------------------------------------

typedef unsigned int uint4v __attribute__((ext_vector_type(4)));

#define NPB 1024            // nodes per bucket
#define NPB_SHIFT 10
#define NPB_MASK (NPB - 1)
#define MAXB 512            // max buckets
#define P1T 512             // k_bucket threads
#define CHUNK 16384         // edges per k_bucket block
#define EPT 32              // CHUNK / P1T edges per thread
#define SORT_CAP 17408      // per-bucket file capacity
#define SPT 17              // SORT_CAP / 1024 entries per k_sort thread
#define AGG_T 1024          // agg block threads (one block per bucket)

__device__ __forceinline__ unsigned short f2bf(float f) {
    unsigned int x = __float_as_uint(f);
    x += 0x7fffu + ((x >> 16) & 1u);            // round-to-nearest-even
    return (unsigned short)(x >> 16);
}
__device__ __forceinline__ float bf2f(unsigned short h) {
    return __uint_as_float((unsigned int)h << 16);
}

// ---------------------------------------------------------------------------
// Phase 1: bucket by dst>>10. One LDS atomic per edge (rank-first).
// ---------------------------------------------------------------------------
__global__ __launch_bounds__(P1T) void k_bucket(
    const int* __restrict__ src, const int* __restrict__ dst,
    unsigned int* __restrict__ file, int* __restrict__ ctr,
    int E, int nbucket, int cap)
{
    __shared__ unsigned int sorted[CHUNK];   // 64 KB
    __shared__ int rk[MAXB];                 // rank counters -> histogram
    __shared__ int pre[MAXB + 1];
    __shared__ int gb[MAXB];
    __shared__ int wsum[P1T / 64];

    const int t  = threadIdx.x;
    const int e0 = blockIdx.x * CHUNK;
    const int nE = min(CHUNK, E - e0);

    for (int b = t; b < MAXB; b += P1T) rk[b] = 0;
    __syncthreads();

    const bool full = (nE == CHUNK);
    int4 dc[8];          // cached dst
    int  rnk[EPT];       // cached ranks

    // ---- pass 1: rank assignment (doubles as histogram) ----
    if (full) {
        const int4* d4 = (const int4*)(dst + e0);
#pragma unroll
        for (int k = 0; k < 8; ++k) dc[k] = d4[t + k * P1T];
#pragma unroll
        for (int k = 0; k < 8; ++k) {
            rnk[4 * k]     = atomicAdd(&rk[((unsigned)dc[k].x) >> NPB_SHIFT], 1);
            rnk[4 * k + 1] = atomicAdd(&rk[((unsigned)dc[k].y) >> NPB_SHIFT], 1);
            rnk[4 * k + 2] = atomicAdd(&rk[((unsigned)dc[k].z) >> NPB_SHIFT], 1);
            rnk[4 * k + 3] = atomicAdd(&rk[((unsigned)dc[k].w) >> NPB_SHIFT], 1);
        }
    } else {
        int k = 0;
        for (int i = t; i < nE; i += P1T, ++k)
            rnk[k] = atomicAdd(&rk[((unsigned)dst[e0 + i]) >> NPB_SHIFT], 1);
    }
    __syncthreads();

    // ---- hierarchical inclusive scan of rk -> pre (3 barriers) ----
    {
        const int lane = t & 63, wv = t >> 6;
        int v = (t < nbucket) ? rk[t] : 0;
#pragma unroll
        for (int d = 1; d < 64; d <<= 1) {
            int nv = __shfl_up(v, d, 64);
            if (lane >= d) v += nv;
        }
        if (lane == 63) wsum[wv] = v;
        __syncthreads();
        if (t < P1T / 64) {
            int s = wsum[t];
#pragma unroll
            for (int d = 1; d < P1T / 64; d <<= 1) {
                int ns = __shfl_up(s, d, P1T / 64);
                if (t >= d) s += ns;
            }
            wsum[t] = s;
        }
        __syncthreads();
        pre[t + 1] = (wv ? wsum[wv - 1] : 0) + v;
        if (t == 0) pre[0] = 0;
    }
    __syncthreads();

    // ---- reserve global space per (block,bucket) ----
    for (int b = t; b < nbucket; b += P1T) {
        int c = pre[b + 1] - pre[b];
        gb[b] = c ? atomicAdd(&ctr[b], c) : 0;
    }
    __syncthreads();

    // ---- pass 2: scatter into LDS using saved ranks (no atomics) ----
    if (full) {
        const int4* s4 = (const int4*)(src + e0);
#pragma unroll
        for (int k = 0; k < 8; ++k) {
            int4 s = s4[t + k * P1T];
            int4 d = dc[k];
            sorted[pre[((unsigned)d.x) >> NPB_SHIFT] + rnk[4 * k]] =
                (((unsigned)s.x) << NPB_SHIFT) | ((unsigned)d.x & NPB_MASK);
            sorted[pre[((unsigned)d.y) >> NPB_SHIFT] + rnk[4 * k + 1]] =
                (((unsigned)s.y) << NPB_SHIFT) | ((unsigned)d.y & NPB_MASK);
            sorted[pre[((unsigned)d.z) >> NPB_SHIFT] + rnk[4 * k + 2]] =
                (((unsigned)s.z) << NPB_SHIFT) | ((unsigned)d.z & NPB_MASK);
            sorted[pre[((unsigned)d.w) >> NPB_SHIFT] + rnk[4 * k + 3]] =
                (((unsigned)s.w) << NPB_SHIFT) | ((unsigned)d.w & NPB_MASK);
        }
    } else {
        int k = 0;
        for (int i = t; i < nE; i += P1T, ++k) {
            int d = dst[e0 + i];
            int b = ((unsigned)d) >> NPB_SHIFT;
            sorted[pre[b] + rnk[k]] =
                (((unsigned)src[e0 + i]) << NPB_SHIFT) | ((unsigned)d & NPB_MASK);
        }
    }
    __syncthreads();

    // ---- pass 3: per-wave run write-out, clamped to cap ----
    {
        const int wid  = t >> 6;
        const int lane = t & 63;
        const int nw   = P1T >> 6;
        for (int b = wid; b < nbucket; b += nw) {
            int s0 = pre[b], s1 = pre[b + 1];
            int base = gb[b];
            unsigned int* dp = file + (size_t)b * cap;
            for (int j = s0 + lane; j < s1; j += 64) {
                int idx = base + (j - s0);
                if (idx < cap)
                    __builtin_nontemporal_store(sorted[j], &dp[idx]);
            }
        }
    }
}

// ---------------------------------------------------------------------------
// Phase 2: per-bucket sort by dstlo; write back FULL sorted entries.
// ---------------------------------------------------------------------------
__global__ __launch_bounds__(NPB) void k_sort(
    unsigned int* __restrict__ file, const int* __restrict__ ctr,
    const float* __restrict__ x, float* __restrict__ dinv,
    unsigned short* __restrict__ u, int N, int cap)
{
    __shared__ unsigned int sorted[SORT_CAP];  // 69.6 KB
    __shared__ int cnt[NPB];
    __shared__ int pre[NPB + 1];
    __shared__ int wsum[NPB / 64];

    const int t = threadIdx.x;
    const int b = blockIdx.x;
    const int nb = min(ctr[b], cap);
    unsigned int* f = file + (size_t)b * cap;

    cnt[t] = 0;
    __syncthreads();

    unsigned int ev[SPT];
    int rk_[SPT];
#pragma unroll
    for (int k = 0; k < SPT; ++k) {
        int i = t + (k << NPB_SHIFT);
        if (i < nb) ev[k] = __builtin_nontemporal_load(f + i);
    }
#pragma unroll
    for (int k = 0; k < SPT; ++k) {
        int i = t + (k << NPB_SHIFT);
        if (i < nb) rk_[k] = atomicAdd(&cnt[ev[k] & NPB_MASK], 1);
    }
    __syncthreads();

    // hierarchical inclusive scan of cnt -> pre (3 barriers)
    {
        const int lane = t & 63, wv = t >> 6;
        int v = cnt[t];
#pragma unroll
        for (int d = 1; d < 64; d <<= 1) {
            int nv = __shfl_up(v, d, 64);
            if (lane >= d) v += nv;
        }
        if (lane == 63) wsum[wv] = v;
        __syncthreads();
        if (t < NPB / 64) {
            int s = wsum[t];
#pragma unroll
            for (int d = 1; d < NPB / 64; d <<= 1) {
                int ns = __shfl_up(s, d, NPB / 64);
                if (t >= d) s += ns;
            }
            wsum[t] = s;
        }
        __syncthreads();
        pre[t + 1] = (wv ? wsum[wv - 1] : 0) + v;
        if (t == 0) pre[0] = 0;
    }
    __syncthreads();

    // scatter FULL entries into dst-sorted LDS order
#pragma unroll
    for (int k = 0; k < SPT; ++k) {
        int i = t + (k << NPB_SHIFT);
        if (i < nb)
            sorted[pre[ev[k] & NPB_MASK] + rk_[k]] = ev[k];
    }
    __syncthreads();

    // coalesced in-place write-back (write-once; nt ok)
    for (int i = t; i < nb; i += NPB)
        __builtin_nontemporal_store(sorted[i], &f[i]);

    // node epilogue
    const int g = b * NPB + t;
    if (g < N) {
        float dv = rsqrtf((float)(cnt[t] + 1));   // +1 self-loop
        dinv[g] = dv;
        u[g] = f2bf(x[g] * dv);
    }
}

// ---------------------------------------------------------------------------
// Phase 3: segmented-reduce agg1 -> MLP -> q (2xbf16). One block per bucket.
// ---------------------------------------------------------------------------
__global__ __launch_bounds__(AGG_T) void k_agg1(
    const unsigned int* __restrict__ file, const int* __restrict__ ctr,
    const unsigned short* __restrict__ u, const float* __restrict__ dinv,
    const float* __restrict__ W1, const float* __restrict__ b1,
    const float* __restrict__ W2, unsigned int* __restrict__ q,
    int N, int cap)
{
    __shared__ float acc[NPB];
    const int t = threadIdx.x;
    const int b = blockIdx.x;
    const int lane = t & 63;
    const int nb = min(ctr[b], cap);
    const unsigned int* f = file + (size_t)b * cap;

    acc[t] = 0.f;
    __syncthreads();

    const int nbr = (nb + 63) & ~63;
    for (int i = t; i < nbr; i += AGG_T) {
        bool valid = (i < nb);
        unsigned int w = valid ? __builtin_nontemporal_load(f + i) : 0u;
        int key = valid ? (int)(w & NPB_MASK) : -1;
        float val = valid ? bf2f(u[w >> NPB_SHIFT]) : 0.f;
        // segmented inclusive scan by key within the wave (entries sorted)
#pragma unroll
        for (int d = 1; d < 64; d <<= 1) {
            float nv = __shfl_up(val, d, 64);
            int   nk = __shfl_up(key, d, 64);
            if (lane >= d && nk == key) val += nv;
        }
        int kd = __shfl_down(key, 1, 64);
        if (valid && (lane == 63 || kd != key))
            atomicAdd(&acc[key], val);          // ~1 per run tail (~E/16)
    }
    __syncthreads();

    const int g = b * NPB + t;
    if (g < N) {
        float dv = dinv[g];
        float s1v = (acc[t] + bf2f(u[g])) * dv;
        float c0 = 0.f, c1 = 0.f;
#pragma unroll
        for (int k = 0; k < 16; ++k) {
            float h = fmaxf(fmaf(s1v, W1[k], b1[k]), 0.f);
            c0 = fmaf(h, W2[2 * k], c0);
            c1 = fmaf(h, W2[2 * k + 1], c1);
        }
        q[g] = (unsigned int)f2bf(c0 * dv) | ((unsigned int)f2bf(c1 * dv) << 16);
    }
}

// ---------------------------------------------------------------------------
// Phase 4: segmented-reduce agg2 (2 planes) -> log_softmax.
// ---------------------------------------------------------------------------
__global__ __launch_bounds__(AGG_T) void k_agg2(
    const unsigned int* __restrict__ file, const int* __restrict__ ctr,
    const unsigned int* __restrict__ q, const float* __restrict__ dinv,
    const float* __restrict__ b2, float2* __restrict__ out,
    int N, int cap)
{
    __shared__ float a0s[NPB];
    __shared__ float a1s[NPB];
    const int t = threadIdx.x;
    const int b = blockIdx.x;
    const int lane = t & 63;
    const int nb = min(ctr[b], cap);
    const unsigned int* f = file + (size_t)b * cap;

    a0s[t] = 0.f;
    a1s[t] = 0.f;
    __syncthreads();

    const int nbr = (nb + 63) & ~63;
    for (int i = t; i < nbr; i += AGG_T) {
        bool valid = (i < nb);
        unsigned int w = valid ? __builtin_nontemporal_load(f + i) : 0u;
        int key = valid ? (int)(w & NPB_MASK) : -1;
        float v0 = 0.f, v1 = 0.f;
        if (valid) {
            unsigned int gq = q[w >> NPB_SHIFT];
            v0 = bf2f((unsigned short)gq);
            v1 = bf2f((unsigned short)(gq >> 16));
        }
#pragma unroll
        for (int d = 1; d < 64; d <<= 1) {
            float n0 = __shfl_up(v0, d, 64);
            float n1 = __shfl_up(v1, d, 64);
            int   nk = __shfl_up(key, d, 64);
            if (lane >= d && nk == key) { v0 += n0; v1 += n1; }
        }
        int kd = __shfl_down(key, 1, 64);
        if (valid && (lane == 63 || kd != key)) {
            atomicAdd(&a0s[key], v0);
            atomicAdd(&a1s[key], v1);
        }
    }
    __syncthreads();

    const int g = b * NPB + t;
    if (g < N) {
        float dv = dinv[g];
        unsigned int qi = q[g];
        float o0 = (a0s[t] + bf2f((unsigned short)qi)) * dv + b2[0];
        float o1 = (a1s[t] + bf2f((unsigned short)(qi >> 16))) * dv + b2[1];
        float m = fmaxf(o0, o1);
        float l = m + logf(expf(o0 - m) + expf(o1 - m));
        out[g] = make_float2(o0 - l, o1 - l);
    }
}

// ===========================================================================
// Fallback path (direct-atomic, fp32) if workspace/shape doesn't fit.
// ===========================================================================
#define NT 256
__global__ __launch_bounds__(NT) void fb_deg(const int* __restrict__ dst,
                                             int* __restrict__ deg, int E) {
    int e = blockIdx.x * blockDim.x + threadIdx.x;
    if (e < E) atomicAdd(&deg[dst[e]], 1);
}
__global__ __launch_bounds__(NT) void fb_node1(const float* __restrict__ x,
                                               const int* __restrict__ deg,
                                               float* __restrict__ dinv,
                                               float* __restrict__ u, int N) {
    int i = blockIdx.x * blockDim.x + threadIdx.x;
    if (i < N) {
        float dv = rsqrtf((float)(deg[i] + 1));
        dinv[i] = dv;
        u[i] = x[i] * dv;
    }
}
__global__ __launch_bounds__(NT) void fb_edge1(const int* __restrict__ src,
                                               const int* __restrict__ dst,
                                               const float* __restrict__ u,
                                               float* __restrict__ agg1, int E) {
    int e = blockIdx.x * blockDim.x + threadIdx.x;
    if (e < E) atomicAdd(&agg1[dst[e]], u[src[e]]);
}
__global__ __launch_bounds__(NT) void fb_node2(const float* __restrict__ agg1,
                                               const float* __restrict__ u,
                                               const float* __restrict__ dinv,
                                               const float* __restrict__ W1,
                                               const float* __restrict__ b1,
                                               const float* __restrict__ W2,
                                               float2* __restrict__ q, int N) {
    int i = blockIdx.x * blockDim.x + threadIdx.x;
    if (i < N) {
        float dv = dinv[i];
        float s1 = (agg1[i] + u[i]) * dv;
        float c0 = 0.f, c1 = 0.f;
#pragma unroll
        for (int k = 0; k < 16; ++k) {
            float h = fmaxf(fmaf(s1, W1[k], b1[k]), 0.f);
            c0 = fmaf(h, W2[2 * k], c0);
            c1 = fmaf(h, W2[2 * k + 1], c1);
        }
        q[i] = make_float2(c0 * dv, c1 * dv);
    }
}
__global__ __launch_bounds__(NT) void fb_edge2(const int* __restrict__ src,
                                               const int* __restrict__ dst,
                                               const float2* __restrict__ q,
                                               float* __restrict__ agg2, int E) {
    int e = blockIdx.x * blockDim.x + threadIdx.x;
    if (e < E) {
        float2 qq = q[src[e]];
        atomicAdd(&agg2[2 * dst[e]], qq.x);
        atomicAdd(&agg2[2 * dst[e] + 1], qq.y);
    }
}
__global__ __launch_bounds__(NT) void fb_node3(const float* __restrict__ agg2,
                                               const float2* __restrict__ q,
                                               const float* __restrict__ dinv,
                                               const float* __restrict__ b2,
                                               float2* __restrict__ out, int N) {
    int i = blockIdx.x * blockDim.x + threadIdx.x;
    if (i < N) {
        float dv = dinv[i];
        float2 qi = q[i];
        float o0 = (agg2[2 * i] + qi.x) * dv + b2[0];
        float o1 = (agg2[2 * i + 1] + qi.y) * dv + b2[1];
        float m = fmaxf(o0, o1);
        float l = m + logf(expf(o0 - m) + expf(o1 - m));
        out[i] = make_float2(o0 - l, o1 - l);
    }
}

// ===========================================================================
extern "C" void kernel_launch(void* const* d_in, const int* in_sizes, int n_in,
                              void* d_out, int out_size, void* d_ws, size_t ws_size,
                              hipStream_t stream) {
    const float* x  = (const float*)d_in[0];
    const int* ei   = (const int*)d_in[1];
    const float* W1 = (const float*)d_in[2];
    const float* b1 = (const float*)d_in[3];
    const float* W2 = (const float*)d_in[4];
    const float* b2 = (const float*)d_in[5];

    const int N = in_sizes[0];
    const int E = in_sizes[1] / 2;
    const int* src = ei;
    const int* dst = ei + E;

    const int nbucket = (N + NPB - 1) / NPB;
    const int cap = ((E / nbucket + 1024) + 63) & ~63;   // must be <= SORT_CAP

    auto align_up = [](size_t v) { return (v + 255) & ~(size_t)255; };
    size_t off_ctr   = 0;
    size_t off_file  = align_up((size_t)MAXB * sizeof(int));
    size_t off_dinv  = align_up(off_file + (size_t)nbucket * SORT_CAP * sizeof(unsigned int));
    size_t off_u     = align_up(off_dinv + (size_t)N * sizeof(float));
    size_t off_q     = align_up(off_u + (size_t)N * sizeof(unsigned short));
    size_t needed    = off_q + (size_t)N * sizeof(unsigned int);

    char* ws = (char*)d_ws;

    if (nbucket <= MAXB && cap <= SORT_CAP && needed <= ws_size) {
        int*            ctr   = (int*)(ws + off_ctr);
        unsigned int*   file  = (unsigned int*)(ws + off_file);
        float*          dinv  = (float*)(ws + off_dinv);
        unsigned short* u     = (unsigned short*)(ws + off_u);
        unsigned int*   q     = (unsigned int*)(ws + off_q);

        (void)hipMemsetAsync(ctr, 0, (size_t)MAXB * sizeof(int), stream);

        const int p1Blocks = (E + CHUNK - 1) / CHUNK;
        k_bucket<<<p1Blocks, P1T, 0, stream>>>(src, dst, file, ctr, E, nbucket, SORT_CAP);
        k_sort  <<<nbucket, NPB, 0, stream>>>(file, ctr, x, dinv, u, N, SORT_CAP);
        k_agg1  <<<nbucket, AGG_T, 0, stream>>>(file, ctr, u, dinv, W1, b1, W2, q, N, SORT_CAP);
        k_agg2  <<<nbucket, AGG_T, 0, stream>>>(file, ctr, q, dinv, b2, (float2*)d_out, N, SORT_CAP);
    } else {
        int*    deg  = (int*)   (ws);
        float*  agg1 = (float*) (ws + (size_t)4 * N);
        float*  agg2 = (float*) (ws + (size_t)8 * N);
        float*  dinv = (float*) (ws + (size_t)16 * N);
        float*  u    = (float*) (ws + (size_t)20 * N);
        float2* q    = (float2*)(ws + (size_t)24 * N);
        (void)hipMemsetAsync(ws, 0, (size_t)16 * N, stream);
        const int nodeBlocks = (N + NT - 1) / NT;
        const int edgeBlocks = (E + NT - 1) / NT;
        fb_deg  <<<edgeBlocks, NT, 0, stream>>>(dst, deg, E);
        fb_node1<<<nodeBlocks, NT, 0, stream>>>(x, deg, dinv, u, N);
        fb_edge1<<<edgeBlocks, NT, 0, stream>>>(src, dst, u, agg1, E);
        fb_node2<<<nodeBlocks, NT, 0, stream>>>(agg1, u, dinv, W1, b1, W2, q, N);
        fb_edge2<<<edgeBlocks, NT, 0, stream>>>(src, dst, q, agg2, E);
        fb_node3<<<nodeBlocks, NT, 0, stream>>>(agg2, q, dinv, b2, (float2*)d_out, N);
    }
}